// Round 18
// baseline (19.270 us; speedup 1.0000x reference)
//
#include <hip/hip_runtime.h>
#include <hip/hip_bf16.h>

#define TOKENS 32
#define KDIM   4096
#define NDIM   11008
#define GSZ    64
#define KP     (KDIM/2)          // qweight row length in int32 (2048)
#define NGRP   (KDIM/GSZ)        // 64 groups
#define OUTK   8                 // K-splits across blocks (== 8 XCDs, ob=bi&7)
#define BLK_COLS 128             // 4 colWaves * 32 cols
#define NBLK_C (NDIM/BLK_COLS)   // 86
#define KSLICE (KDIM/OUTK)       // 512 k per block
#define GPW    (KSLICE/2/GSZ)    // 4 groups per wave (2 inner ksegs)
#define PART_ELEMS (TOKENS*NDIM) // 352256

typedef float  f32x4 __attribute__((ext_vector_type(4)));
typedef int    i32x4 __attribute__((ext_vector_type(4)));
typedef short  s16x8 __attribute__((ext_vector_type(8)));
typedef _Float16 f16x2 __attribute__((ext_vector_type(2)));
typedef _Float16 f16x4 __attribute__((ext_vector_type(4)));
typedef _Float16 f16x8 __attribute__((ext_vector_type(8)));

__device__ __forceinline__ void gload_lds16(const void* g, void* l) {
    __builtin_amdgcn_global_load_lds(
        (const __attribute__((address_space(1))) unsigned int*)g,
        (__attribute__((address_space(3))) unsigned int*)l, 16, 0, 0);
}
__device__ __forceinline__ void gload_lds4(const void* g, void* l) {
    __builtin_amdgcn_global_load_lds(
        (const __attribute__((address_space(1))) unsigned int*)g,
        (__attribute__((address_space(3))) unsigned int*)l, 4, 0, 0);
}

// Main GEMM: grid = 688 blocks, 512 thr = 8 waves.  (r17 math, 18.9us base.)
// ob = blockIdx & 7 -> one outer-kseg per XCD (keep: r15 lesson).
// NEW (r18): K-loop operands arrive via per-wave async DMA double-buffer in
// LDS (T3-lite). Per wave per group: q = 8 rows x 128B = 1KB = ONE
// global_load_lds width16 (lane l -> row l&7, chunk l>>3; LDS linear l*16);
// s/z = 256B = ONE width4 (lane<32: sc, else zp). No global loads in the
// K-loop; no GD registers (r11: VGPR=44 proved reg-prefetch never
// materializes; reg pipeline deep enough needs VGPR>64 which kills the
// 3-blocks/CU co-residency, the r12/r16 confound). Counted vmcnt waits,
// lgkmcnt(0)+sched_barrier before buffer reuse (rule #18).
// DEQUANT f16 packed (exact -1024 subtract); partials f16 (r17).
__global__ __launch_bounds__(512, 6) void awq_gemm2(
    const int* __restrict__ qw, const float* __restrict__ sc,
    const float* __restrict__ zp, const float* __restrict__ xf,
    _Float16* __restrict__ partial) {
    __shared__ unsigned short xs[TOKENS * KSLICE];   // 32 KB (reused for reduce)
    __shared__ char qz[8][2][1280];                  // 20 KB: [wave][buf] q1KB+sz256B

    const int tid  = threadIdx.x;
    const int lane = tid & 63;
    const int wid  = tid >> 6;       // 0..7
    const int cw   = wid & 3;        // colWave
    const int ks   = wid >> 2;       // inner kseg 0..1
    const int ob   = blockIdx.x & 7;         // outer kseg == XCD
    const int bc   = blockIdx.x >> 3;        // col group 0..85
    const int K0   = ob * KSLICE;

    const int col  = lane & 15;
    const int kg   = lane >> 4;                      // k-subgroup 0..3
    const int n0   = bc * BLK_COLS + cw * 32 + col;  // colset-0 column
    const int sh0  = 8 * (n0 & 3);

    // ---- per-wave async DMA of one group's q + s/z into LDS buf b ----
    auto DMAQ = [&](int gl, int b) {
        const int gg = ob * (NGRP / OUTK) + ks * GPW + gl;
        const int row = bc * 32 + cw * 8 + (lane & 7);
        const int* qsrc = qw + (size_t)row * KP + gg * 32 + (lane >> 3) * 4;
        gload_lds16(qsrc, &qz[wid][b][0]);           // lane l -> byte l*16
        const float* szsrc = (lane < 32 ? sc : zp) + gg * NDIM
                             + bc * BLK_COLS + cw * 32 + (lane & 31);
        gload_lds4(szsrc, &qz[wid][b][1024]);        // lane l -> byte 1024+l*4
    };

    // ---- q-prefetch for groups 0/1 issued BEFORE x staging ----
    DMAQ(0, 0);
    DMAQ(1, 1);

    // ---- stage x slice: f32 global -> f16 swizzled LDS (32KB) ----
#pragma unroll
    for (int it = 0; it < 4; ++it) {
        const int lin  = it * 8192 + tid * 16;       // byte offset in f16 slice
        const int tok  = lin >> 10;
        const int kloc = (lin & 1023) >> 1;
        const float* xp = xf + tok * KDIM + K0 + kloc;
        f32x4 u0 = *reinterpret_cast<const f32x4*>(xp);
        f32x4 u1 = *reinterpret_cast<const f32x4*>(xp + 4);
        s16x8 v;
#pragma unroll
        for (int e = 0; e < 4; ++e) {
            v[e]     = __builtin_bit_cast(short, (_Float16)u0[e]);
            v[e + 4] = __builtin_bit_cast(short, (_Float16)u1[e]);
        }
        *reinterpret_cast<s16x8*>(
            reinterpret_cast<char*>(xs) + (lin ^ ((tok & 7) << 4))) = v;
    }
    __syncthreads();   // drains vmcnt(0): x staged AND q bufs 0/1 landed

    f32x4 acc00 = {0,0,0,0}, acc01 = {0,0,0,0};      // [colset][Mtile]
    f32x4 acc10 = {0,0,0,0}, acc11 = {0,0,0,0};

    auto LDSA = [&](int tok, int c) -> f16x8 {       // a-frag from swizzled LDS
        const int inrow = ((c << 6) + (kg << 4)) ^ ((tok & 7) << 4);
        return *reinterpret_cast<const f16x8*>(
            reinterpret_cast<const char*>(xs) + (tok << 10) + inrow);
    };

    const f16x2 m1024 = {(_Float16)(-1024.0f), (_Float16)(-1024.0f)};

    auto DQ = [&](const i32x4& q, f16x2 s2, f16x2 c2) -> f16x8 {
        i32x4 wu;
#pragma unroll
        for (int dd = 0; dd < 4; ++dd) {
            const int t = q[dd] >> sh0;
            const unsigned u = (unsigned)((t & 15) | ((t & 0xF0) << 12)) | 0x64006400u;
            f16x2 qv = __builtin_bit_cast(f16x2, u);
            f16x2 q2 = qv + m1024;                   // exact: q as f16 pair
            f16x2 w  = __builtin_elementwise_fma(q2, s2, c2);
            wu[dd] = __builtin_bit_cast(int, w);
        }
        return __builtin_bit_cast(f16x8, wu);
    };

    struct FR { i32x4 qa0, qa1, qb0, qb1; float s0, z0, s1, z1; };

    auto LOADF = [&](FR& f, int b) {                 // LDS -> regs for one group
        const char*  qp  = &qz[wid][b][0];
        const float* szp = reinterpret_cast<const float*>(&qz[wid][b][1024]);
        const int rr = col >> 2;                     // LDS slot (rr,c)=c*128+rr*16
        f.qa0 = *reinterpret_cast<const i32x4*>(qp + kg * 128 + rr * 16);
        f.qa1 = *reinterpret_cast<const i32x4*>(qp + (kg + 4) * 128 + rr * 16);
        f.qb0 = *reinterpret_cast<const i32x4*>(qp + kg * 128 + (rr + 4) * 16);
        f.qb1 = *reinterpret_cast<const i32x4*>(qp + (kg + 4) * 128 + (rr + 4) * 16);
        f.s0 = szp[col];      f.s1 = szp[col + 16];
        f.z0 = szp[32 + col]; f.z1 = szp[32 + col + 16];
    };

    auto MATH = [&](const FR& f, int gl) {
        const int c0 = ks * 8 + gl * 2;              // local K32-chunk
        f16x8 a00 = LDSA(col, c0),      a01 = LDSA(col + 16, c0);
        f16x8 a10 = LDSA(col, c0 + 1),  a11 = LDSA(col + 16, c0 + 1);
        const _Float16 hs0 = (_Float16)f.s0, hs1 = (_Float16)f.s1;
        const _Float16 hc0 = (_Float16)(-f.z0 * f.s0);
        const _Float16 hc1 = (_Float16)(-f.z1 * f.s1);
        const f16x2 s20 = {hs0, hs0}, c20 = {hc0, hc0};
        const f16x2 s21 = {hs1, hs1}, c21 = {hc1, hc1};
        f16x8 w00 = DQ(f.qa0, s20, c20), w01 = DQ(f.qa1, s20, c20);
        f16x8 w10 = DQ(f.qb0, s21, c21), w11 = DQ(f.qb1, s21, c21);
        acc00 = __builtin_amdgcn_mfma_f32_16x16x32_f16(a00, w00, acc00, 0, 0, 0);
        acc01 = __builtin_amdgcn_mfma_f32_16x16x32_f16(a01, w00, acc01, 0, 0, 0);
        acc10 = __builtin_amdgcn_mfma_f32_16x16x32_f16(a00, w10, acc10, 0, 0, 0);
        acc11 = __builtin_amdgcn_mfma_f32_16x16x32_f16(a01, w10, acc11, 0, 0, 0);
        acc00 = __builtin_amdgcn_mfma_f32_16x16x32_f16(a10, w01, acc00, 0, 0, 0);
        acc01 = __builtin_amdgcn_mfma_f32_16x16x32_f16(a11, w01, acc01, 0, 0, 0);
        acc10 = __builtin_amdgcn_mfma_f32_16x16x32_f16(a10, w11, acc10, 0, 0, 0);
        acc11 = __builtin_amdgcn_mfma_f32_16x16x32_f16(a11, w11, acc11, 0, 0, 0);
    };

    // ---- K-loop, unrolled 4 groups, 2-deep LDS double-buffer ----
    FR f;
    LOADF(f, 0);                                     // group 0 from buf0
    asm volatile("s_waitcnt lgkmcnt(0)" ::: "memory");  // reads done before
    __builtin_amdgcn_sched_barrier(0);                  // ...buf0 is re-DMA'd
    DMAQ(2, 0);
    MATH(f, 0);

    LOADF(f, 1);                                     // group 1 from buf1
    asm volatile("s_waitcnt lgkmcnt(0)" ::: "memory");
    __builtin_amdgcn_sched_barrier(0);
    DMAQ(3, 1);
    MATH(f, 1);

    asm volatile("s_waitcnt vmcnt(2)" ::: "memory"); // pair(2) landed in buf0
    __builtin_amdgcn_sched_barrier(0);
    LOADF(f, 0);
    MATH(f, 2);

    asm volatile("s_waitcnt vmcnt(0)" ::: "memory"); // pair(3) landed in buf1
    __builtin_amdgcn_sched_barrier(0);
    LOADF(f, 1);
    MATH(f, 3);

    // ---- inner-kseg reduction through LDS (reuse xs) ----
    __syncthreads();
    float (*red)[64][17] = reinterpret_cast<float (*)[64][17]>(xs);
    if (ks == 1) {
#pragma unroll
        for (int e = 0; e < 4; ++e) {
            red[cw][lane][e]      = acc00[e];
            red[cw][lane][4 + e]  = acc01[e];
            red[cw][lane][8 + e]  = acc10[e];
            red[cw][lane][12 + e] = acc11[e];
        }
    }
    __syncthreads();
    if (ks == 0) {
#pragma unroll
        for (int e = 0; e < 4; ++e) {
            acc00[e] += red[cw][lane][e];
            acc01[e] += red[cw][lane][4 + e];
            acc10[e] += red[cw][lane][8 + e];
            acc11[e] += red[cw][lane][12 + e];
        }
        // D layout (verified m89/m91): col = lane&15, row = (lane>>4)*4 + r
        _Float16* pb = partial + (size_t)ob * PART_ELEMS;
#pragma unroll
        for (int r = 0; r < 4; ++r) {
            const int t = kg * 4 + r;
            pb[t * NDIM + n0]             = (_Float16)acc00[r];
            pb[(t + 16) * NDIM + n0]      = (_Float16)acc01[r];
            pb[t * NDIM + n0 + 16]        = (_Float16)acc10[r];
            pb[(t + 16) * NDIM + n0 + 16] = (_Float16)acc11[r];
        }
    }
}

// Epilogue: out = sum(8 f16 partials) + bias.  88064 4-col slots = 688 x 128.
__global__ __launch_bounds__(128) void awq_epi(
    const _Float16* __restrict__ part, const float* __restrict__ bias,
    float* __restrict__ out) {
    const int i = blockIdx.x * 128 + threadIdx.x;    // 4-col slot, exact fit
    const f16x4* p = reinterpret_cast<const f16x4*>(part);
    f32x4 v = __builtin_convertvector(p[i], f32x4);
#pragma unroll
    for (int o = 1; o < OUTK; ++o)
        v += __builtin_convertvector(p[(size_t)o * (PART_ELEMS / 4) + i], f32x4);
    v += reinterpret_cast<const f32x4*>(bias)[i % (NDIM / 4)];
    reinterpret_cast<f32x4*>(out)[i] = v;
}

// Fallback (ws too small): round-7 kernel, bf16 path, no ws usage.
__global__ __launch_bounds__(256, 3) void awq_gemm_fb(
    const int* __restrict__ qw, const float* __restrict__ sc,
    const float* __restrict__ zp, const float* __restrict__ bias,
    const float* __restrict__ xf, float* __restrict__ out) {
    const int lane = threadIdx.x & 63;
    const int kseg = threadIdx.x >> 6;
    const int col  = lane & 15;
    const int kg   = lane >> 4;
    const int n    = blockIdx.x * 16 + col;
    const int sh0  = 8 * (n & 3);
    const int* qp  = qw + (n >> 2) * KP + kg * 4;
    const int r0 = col, r1 = col + 16;

    f32x4 acc0 = {0,0,0,0}, acc1 = {0,0,0,0};

    auto cvt8 = [](const float* p) {
        f32x4 u0 = *reinterpret_cast<const f32x4*>(p);
        f32x4 u1 = *reinterpret_cast<const f32x4*>(p + 4);
        s16x8 o;
#pragma unroll
        for (int e = 0; e < 4; ++e) {
            o[e]     = __builtin_bit_cast(short, __float2bfloat16(u0[e]));
            o[e + 4] = __builtin_bit_cast(short, __float2bfloat16(u1[e]));
        }
        return o;
    };

    const int g_lo = kseg * (NGRP / 4), g_hi = g_lo + (NGRP / 4);
#pragma unroll 2
    for (int g = g_lo; g < g_hi; ++g) {
        const float s = sc[g * NDIM + n];
        const float bz = -zp[g * NDIM + n] * s;
#pragma unroll
        for (int h = 0; h < 2; ++h) {
            const int chunk = 2 * g + h;
            i32x4 q = *reinterpret_cast<const i32x4*>(qp + chunk * 16);
            const float* p0 = xf + r0 * KDIM + chunk * 32 + kg * 8;
            const float* p1 = xf + r1 * KDIM + chunk * 32 + kg * 8;
            s16x8 a0 = cvt8(p0), a1 = cvt8(p1);
            s16x8 wf;
#pragma unroll
            for (int dd = 0; dd < 4; ++dd) {
                const int qd = q[dd];
                float w0 = (float)((qd >> sh0) & 15) * s + bz;
                float w1 = (float)((qd >> (sh0 + 4)) & 15) * s + bz;
                wf[2 * dd]     = __builtin_bit_cast(short, __float2bfloat16(w0));
                wf[2 * dd + 1] = __builtin_bit_cast(short, __float2bfloat16(w1));
            }
            acc0 = __builtin_amdgcn_mfma_f32_16x16x32_bf16(a0, wf, acc0, 0, 0, 0);
            acc1 = __builtin_amdgcn_mfma_f32_16x16x32_bf16(a1, wf, acc1, 0, 0, 0);
        }
    }

    __shared__ float red[3][64][9];
    if (kseg != 0) {
#pragma unroll
        for (int e = 0; e < 4; ++e) {
            red[kseg - 1][lane][e]     = acc0[e];
            red[kseg - 1][lane][4 + e] = acc1[e];
        }
    }
    __syncthreads();
    if (kseg == 0) {
#pragma unroll
        for (int ss = 0; ss < 3; ++ss)
#pragma unroll
            for (int e = 0; e < 4; ++e) {
                acc0[e] += red[ss][lane][e];
                acc1[e] += red[ss][lane][4 + e];
            }
        const float bv = bias[n];
#pragma unroll
        for (int r = 0; r < 4; ++r) {
            const int t = kg * 4 + r;
            out[t * NDIM + n]        = acc0[r] + bv;
            out[(t + 16) * NDIM + n] = acc1[r] + bv;
        }
    }
}

extern "C" void kernel_launch(void* const* d_in, const int* in_sizes, int n_in,
                              void* d_out, int out_size, void* d_ws, size_t ws_size,
                              hipStream_t stream) {
    const float* x    = (const float*)d_in[0];
    const int*   qw   = (const int*)d_in[1];
    const float* sc   = (const float*)d_in[2];
    const float* zp   = (const float*)d_in[3];
    const float* bias = (const float*)d_in[4];
    float*       out  = (float*)d_out;

    const size_t part_bytes = (size_t)OUTK * PART_ELEMS * sizeof(_Float16); // ~5.6 MB

    if (ws_size >= part_bytes) {
        _Float16* part = (_Float16*)d_ws;
        awq_gemm2<<<NBLK_C * OUTK, 512, 0, stream>>>(qw, sc, zp, x, part);
        awq_epi<<<PART_ELEMS / 4 / 128, 128, 0, stream>>>(part, bias, out);
    } else {
        awq_gemm_fb<<<NDIM / 16, 256, 0, stream>>>(qw, sc, zp, bias, x, out);
    }
}

// Round 19
// 18.146 us; speedup vs baseline: 1.0620x; 1.0620x over previous
//
#include <hip/hip_runtime.h>
#include <hip/hip_bf16.h>

#define TOKENS 32
#define KDIM   4096
#define NDIM   11008
#define GSZ    64
#define KP     (KDIM/2)          // qweight row length in int32 (2048)
#define NGRP   (KDIM/GSZ)        // 64 groups
#define OUTK   8                 // K-splits across blocks (== 8 XCDs, ob=bi&7)
#define BLK_COLS 128             // 4 colWaves * 32 cols
#define NBLK_C (NDIM/BLK_COLS)   // 86
#define KSLICE (KDIM/OUTK)       // 512 k per block
#define GPW    (KSLICE/2/GSZ)    // 4 groups per wave (2 inner ksegs)
#define PART_ELEMS (TOKENS*NDIM) // 352256

typedef float  f32x4 __attribute__((ext_vector_type(4)));
typedef float  f32x8 __attribute__((ext_vector_type(8)));
typedef int    i32x4 __attribute__((ext_vector_type(4)));
typedef short  s16x8 __attribute__((ext_vector_type(8)));
typedef _Float16 f16x2 __attribute__((ext_vector_type(2)));
typedef _Float16 f16x8 __attribute__((ext_vector_type(8)));

// Main GEMM: grid = 688 blocks, 512 thr = 8 waves.  (r17 structure = best,
// 18.9us. r14 OUTK=4, r15 fused-epi, r16 4-wave, r18 DMA-pipeline all
// regressed/neutral -> K-loop is at its issue floor; remaining term is the
// epilogue's cross-XCD partial reads.)
// ob = blockIdx & 7 -> one outer-kseg per XCD: per-XCD set = q 2.8MB +
// sc/zp 0.7MB + x 64KB < 4MB L2 (r15 lesson: keep ob on the XCD axis).
// NEW (r19): partial stores are NON-TEMPORAL (nt) -> stream to L3 instead of
// sitting dirty in one XCD's L2. The epi reads all 8 obs; without nt, 7/8 of
// those reads are remote-dirty-line snoops across non-coherent L2s (same
// mechanism that torched r15). Epi loads are nt too (no reuse).
// DEQUANT f16 packed (exact -1024 subtract; r5: no large-const FMA folding);
// partials f16 (r17: ~5e-3 rms, zero-mean).
__global__ __launch_bounds__(512, 2) void awq_gemm2(
    const int* __restrict__ qw, const float* __restrict__ sc,
    const float* __restrict__ zp, const float* __restrict__ xf,
    _Float16* __restrict__ partial) {
    __shared__ unsigned short xs[TOKENS * KSLICE];   // 32 KB (reused for reduce)

    const int tid  = threadIdx.x;
    const int lane = tid & 63;
    const int wid  = tid >> 6;       // 0..7
    const int cw   = wid & 3;        // colWave
    const int ks   = wid >> 2;       // inner kseg 0..1
    const int ob   = blockIdx.x & 7;         // outer kseg == XCD
    const int bc   = blockIdx.x >> 3;        // col group 0..85
    const int K0   = ob * KSLICE;

    const int col  = lane & 15;
    const int kg   = lane >> 4;                      // k-subgroup 0..3
    const int n0   = bc * BLK_COLS + cw * 32 + col;  // colset-0 column
    const int sh0  = 8 * (n0 & 3);
    const int* qp0 = qw + (n0 >> 2) * KP + kg * 4;   // colset-1 = +4*KP ints

    struct GD { float s0, z0, s1, z1; i32x4 qa0, qa1, qb0, qb1; };

    auto LOADG = [&](GD& d, int gl) {
        gl = gl < GPW ? gl : GPW - 1;                // clamp prefetch overhang
        const int gg = ob * (NGRP / OUTK) + ks * GPW + gl;  // global group
        d.s0 = sc[gg * NDIM + n0];        d.z0 = zp[gg * NDIM + n0];
        d.s1 = sc[gg * NDIM + n0 + 16];   d.z1 = zp[gg * NDIM + n0 + 16];
        const int* q = qp0 + gg * 32;
        d.qa0 = *reinterpret_cast<const i32x4*>(q);
        d.qa1 = *reinterpret_cast<const i32x4*>(q + 16);
        d.qb0 = *reinterpret_cast<const i32x4*>(q + 4 * KP);
        d.qb1 = *reinterpret_cast<const i32x4*>(q + 4 * KP + 16);
    };

    // ---- q-prefetch for groups 0/1 issued BEFORE staging ----
    GD gA, gB;
    LOADG(gA, 0);
    LOADG(gB, 1);

    // ---- stage x slice: f32 global -> f16 swizzled LDS (32KB) ----
#pragma unroll
    for (int it = 0; it < 4; ++it) {
        const int lin  = it * 8192 + tid * 16;       // byte offset in f16 slice
        const int tok  = lin >> 10;
        const int kloc = (lin & 1023) >> 1;
        const float* xp = xf + tok * KDIM + K0 + kloc;
        f32x4 u0 = *reinterpret_cast<const f32x4*>(xp);
        f32x4 u1 = *reinterpret_cast<const f32x4*>(xp + 4);
        s16x8 v;
#pragma unroll
        for (int e = 0; e < 4; ++e) {
            v[e]     = __builtin_bit_cast(short, (_Float16)u0[e]);
            v[e + 4] = __builtin_bit_cast(short, (_Float16)u1[e]);
        }
        *reinterpret_cast<s16x8*>(
            reinterpret_cast<char*>(xs) + (lin ^ ((tok & 7) << 4))) = v;
    }
    __syncthreads();

    f32x4 acc00 = {0,0,0,0}, acc01 = {0,0,0,0};      // [colset][Mtile]
    f32x4 acc10 = {0,0,0,0}, acc11 = {0,0,0,0};

    auto LDSA = [&](int tok, int c) -> f16x8 {       // a-frag from swizzled LDS
        const int inrow = ((c << 6) + (kg << 4)) ^ ((tok & 7) << 4);
        return *reinterpret_cast<const f16x8*>(
            reinterpret_cast<const char*>(xs) + (tok << 10) + inrow);
    };

    const f16x2 m1024 = {(_Float16)(-1024.0f), (_Float16)(-1024.0f)};

    auto DQ = [&](const i32x4& q, f16x2 s2, f16x2 c2) -> f16x8 {
        i32x4 wu;
#pragma unroll
        for (int dd = 0; dd < 4; ++dd) {
            const int t = q[dd] >> sh0;
            const unsigned u = (unsigned)((t & 15) | ((t & 0xF0) << 12)) | 0x64006400u;
            f16x2 qv = __builtin_bit_cast(f16x2, u);
            f16x2 q2 = qv + m1024;                   // exact: q as f16 pair
            f16x2 w  = __builtin_elementwise_fma(q2, s2, c2);
            wu[dd] = __builtin_bit_cast(int, w);
        }
        return __builtin_bit_cast(f16x8, wu);
    };

    auto COMPUTE = [&](const GD& d, int gl) {
        const int c0 = ks * 8 + gl * 2;              // local K32-chunk
        f16x8 a00 = LDSA(col, c0),      a01 = LDSA(col + 16, c0);
        f16x8 a10 = LDSA(col, c0 + 1),  a11 = LDSA(col + 16, c0 + 1);
        const _Float16 hs0 = (_Float16)d.s0, hs1 = (_Float16)d.s1;
        const _Float16 hc0 = (_Float16)(-d.z0 * d.s0);
        const _Float16 hc1 = (_Float16)(-d.z1 * d.s1);
        const f16x2 s20 = {hs0, hs0}, c20 = {hc0, hc0};
        const f16x2 s21 = {hs1, hs1}, c21 = {hc1, hc1};
        f16x8 w00 = DQ(d.qa0, s20, c20), w01 = DQ(d.qa1, s20, c20);
        f16x8 w10 = DQ(d.qb0, s21, c21), w11 = DQ(d.qb1, s21, c21);
        acc00 = __builtin_amdgcn_mfma_f32_16x16x32_f16(a00, w00, acc00, 0, 0, 0);
        acc01 = __builtin_amdgcn_mfma_f32_16x16x32_f16(a01, w00, acc01, 0, 0, 0);
        acc10 = __builtin_amdgcn_mfma_f32_16x16x32_f16(a00, w10, acc10, 0, 0, 0);
        acc11 = __builtin_amdgcn_mfma_f32_16x16x32_f16(a01, w10, acc11, 0, 0, 0);
        acc00 = __builtin_amdgcn_mfma_f32_16x16x32_f16(a10, w01, acc00, 0, 0, 0);
        acc01 = __builtin_amdgcn_mfma_f32_16x16x32_f16(a11, w01, acc01, 0, 0, 0);
        acc10 = __builtin_amdgcn_mfma_f32_16x16x32_f16(a10, w11, acc10, 0, 0, 0);
        acc11 = __builtin_amdgcn_mfma_f32_16x16x32_f16(a11, w11, acc11, 0, 0, 0);
    };

#pragma unroll
    for (int gl = 0; gl < GPW; gl += 2) {
        COMPUTE(gA, gl);     LOADG(gA, gl + 2);
        COMPUTE(gB, gl + 1); LOADG(gB, gl + 3);
    }

    // ---- inner-kseg reduction through LDS (reuse xs) ----
    __syncthreads();
    float (*red)[64][17] = reinterpret_cast<float (*)[64][17]>(xs);
    if (ks == 1) {
#pragma unroll
        for (int e = 0; e < 4; ++e) {
            red[cw][lane][e]      = acc00[e];
            red[cw][lane][4 + e]  = acc01[e];
            red[cw][lane][8 + e]  = acc10[e];
            red[cw][lane][12 + e] = acc11[e];
        }
    }
    __syncthreads();
    if (ks == 0) {
#pragma unroll
        for (int e = 0; e < 4; ++e) {
            acc00[e] += red[cw][lane][e];
            acc01[e] += red[cw][lane][4 + e];
            acc10[e] += red[cw][lane][8 + e];
            acc11[e] += red[cw][lane][12 + e];
        }
        // D layout (verified m89/m91): col = lane&15, row = (lane>>4)*4 + r
        // NON-TEMPORAL: stream to L3, not dirty-in-local-L2 (epi reads all obs)
        _Float16* pb = partial + (size_t)ob * PART_ELEMS;
#pragma unroll
        for (int r = 0; r < 4; ++r) {
            const int t = kg * 4 + r;
            __builtin_nontemporal_store((_Float16)acc00[r], &pb[t * NDIM + n0]);
            __builtin_nontemporal_store((_Float16)acc01[r], &pb[(t + 16) * NDIM + n0]);
            __builtin_nontemporal_store((_Float16)acc10[r], &pb[t * NDIM + n0 + 16]);
            __builtin_nontemporal_store((_Float16)acc11[r], &pb[(t + 16) * NDIM + n0 + 16]);
        }
    }
}

// Epilogue: out = sum(8 f16 partials) + bias.
// 44032 f16x8 slots = 172 blocks x 256 thr; nt loads (no reuse).
__global__ __launch_bounds__(256) void awq_epi(
    const _Float16* __restrict__ part, const float* __restrict__ bias,
    float* __restrict__ out) {
    const int i = blockIdx.x * 256 + threadIdx.x;    // f16x8 slot, exact fit
    const f16x8* p = reinterpret_cast<const f16x8*>(part);
    f32x8 v = __builtin_convertvector(__builtin_nontemporal_load(&p[i]), f32x8);
#pragma unroll
    for (int o = 1; o < OUTK; ++o)
        v += __builtin_convertvector(
            __builtin_nontemporal_load(&p[(size_t)o * (PART_ELEMS / 8) + i]), f32x8);
    const int bs = i % (NDIM / 8);                   // 8-col slot within row
    const f32x4* bq = reinterpret_cast<const f32x4*>(bias) + bs * 2;
    f32x4 lo = {v[0], v[1], v[2], v[3]}, hi = {v[4], v[5], v[6], v[7]};
    lo += bq[0];
    hi += bq[1];
    f32x4* oq = reinterpret_cast<f32x4*>(out) + (size_t)i * 2;
    oq[0] = lo;
    oq[1] = hi;
}

// Fallback (ws too small): round-7 kernel, bf16 path, no ws usage.
__global__ __launch_bounds__(256, 3) void awq_gemm_fb(
    const int* __restrict__ qw, const float* __restrict__ sc,
    const float* __restrict__ zp, const float* __restrict__ bias,
    const float* __restrict__ xf, float* __restrict__ out) {
    const int lane = threadIdx.x & 63;
    const int kseg = threadIdx.x >> 6;
    const int col  = lane & 15;
    const int kg   = lane >> 4;
    const int n    = blockIdx.x * 16 + col;
    const int sh0  = 8 * (n & 3);
    const int* qp  = qw + (n >> 2) * KP + kg * 4;
    const int r0 = col, r1 = col + 16;

    f32x4 acc0 = {0,0,0,0}, acc1 = {0,0,0,0};

    auto cvt8 = [](const float* p) {
        f32x4 u0 = *reinterpret_cast<const f32x4*>(p);
        f32x4 u1 = *reinterpret_cast<const f32x4*>(p + 4);
        s16x8 o;
#pragma unroll
        for (int e = 0; e < 4; ++e) {
            o[e]     = __builtin_bit_cast(short, __float2bfloat16(u0[e]));
            o[e + 4] = __builtin_bit_cast(short, __float2bfloat16(u1[e]));
        }
        return o;
    };

    const int g_lo = kseg * (NGRP / 4), g_hi = g_lo + (NGRP / 4);
#pragma unroll 2
    for (int g = g_lo; g < g_hi; ++g) {
        const float s = sc[g * NDIM + n];
        const float bz = -zp[g * NDIM + n] * s;
#pragma unroll
        for (int h = 0; h < 2; ++h) {
            const int chunk = 2 * g + h;
            i32x4 q = *reinterpret_cast<const i32x4*>(qp + chunk * 16);
            const float* p0 = xf + r0 * KDIM + chunk * 32 + kg * 8;
            const float* p1 = xf + r1 * KDIM + chunk * 32 + kg * 8;
            s16x8 a0 = cvt8(p0), a1 = cvt8(p1);
            s16x8 wf;
#pragma unroll
            for (int dd = 0; dd < 4; ++dd) {
                const int qd = q[dd];
                float w0 = (float)((qd >> sh0) & 15) * s + bz;
                float w1 = (float)((qd >> (sh0 + 4)) & 15) * s + bz;
                wf[2 * dd]     = __builtin_bit_cast(short, __float2bfloat16(w0));
                wf[2 * dd + 1] = __builtin_bit_cast(short, __float2bfloat16(w1));
            }
            acc0 = __builtin_amdgcn_mfma_f32_16x16x32_bf16(a0, wf, acc0, 0, 0, 0);
            acc1 = __builtin_amdgcn_mfma_f32_16x16x32_bf16(a1, wf, acc1, 0, 0, 0);
        }
    }

    __shared__ float red[3][64][9];
    if (kseg != 0) {
#pragma unroll
        for (int e = 0; e < 4; ++e) {
            red[kseg - 1][lane][e]     = acc0[e];
            red[kseg - 1][lane][4 + e] = acc1[e];
        }
    }
    __syncthreads();
    if (kseg == 0) {
#pragma unroll
        for (int ss = 0; ss < 3; ++ss)
#pragma unroll
            for (int e = 0; e < 4; ++e) {
                acc0[e] += red[ss][lane][e];
                acc1[e] += red[ss][lane][4 + e];
            }
        const float bv = bias[n];
#pragma unroll
        for (int r = 0; r < 4; ++r) {
            const int t = kg * 4 + r;
            out[t * NDIM + n]        = acc0[r] + bv;
            out[(t + 16) * NDIM + n] = acc1[r] + bv;
        }
    }
}

extern "C" void kernel_launch(void* const* d_in, const int* in_sizes, int n_in,
                              void* d_out, int out_size, void* d_ws, size_t ws_size,
                              hipStream_t stream) {
    const float* x    = (const float*)d_in[0];
    const int*   qw   = (const int*)d_in[1];
    const float* sc   = (const float*)d_in[2];
    const float* zp   = (const float*)d_in[3];
    const float* bias = (const float*)d_in[4];
    float*       out  = (float*)d_out;

    const size_t part_bytes = (size_t)OUTK * PART_ELEMS * sizeof(_Float16); // ~5.6 MB

    if (ws_size >= part_bytes) {
        _Float16* part = (_Float16*)d_ws;
        awq_gemm2<<<NBLK_C * OUTK, 512, 0, stream>>>(qw, sc, zp, x, part);
        awq_epi<<<PART_ELEMS / 8 / 256, 256, 0, stream>>>(part, bias, out);
    } else {
        awq_gemm_fb<<<NDIM / 16, 256, 0, stream>>>(qw, sc, zp, bias, x, out);
    }
}